// Round 1
// baseline (408.890 us; speedup 1.0000x reference)
//
#include <hip/hip_runtime.h>
#include <math.h>

#define NFEAT 128
#define NHID  64
#define HC    256   // HEADS*NHID
#define NCLS  16
#define DT_F  0.01f
#define EPS_F 1e-5f

__device__ __forceinline__ float wave_sum(float v) {
#pragma unroll
  for (int m = 32; m > 0; m >>= 1) v += __shfl_xor(v, m);
  return v;
}

// Y = relu(x @ enc_w + enc_b); X = Y.   x:[n,128] w:[128,64]
__global__ __launch_bounds__(256) void enc_kernel(
    const float* __restrict__ x, const float* __restrict__ w,
    const float* __restrict__ b, float* __restrict__ Y, float* __restrict__ X, int n) {
  __shared__ float ws[NFEAT * NHID];  // 32KB
  for (int t = threadIdx.x; t < NFEAT * NHID; t += blockDim.x) ws[t] = w[t];
  __syncthreads();
  const int wave = threadIdx.x >> 6, lane = threadIdx.x & 63;
  for (int i = blockIdx.x * 4 + wave; i < n; i += gridDim.x * 4) {
    const float* xr = x + (size_t)i * NFEAT;
    float acc = b[lane];
#pragma unroll 8
    for (int k = 0; k < NFEAT; ++k) acc = fmaf(xr[k], ws[k * NHID + lane], acc);
    acc = fmaxf(acc, 0.f);
    Y[(size_t)i * NHID + lane] = acc;
    X[(size_t)i * NHID + lane] = acc;
  }
}

// O[n,256] = A[n,64] @ W[64,256] + b  (weights held in registers, rows staged in LDS)
__global__ __launch_bounds__(256) void rowgemm64_256(
    const float* __restrict__ A, const float* __restrict__ W,
    const float* __restrict__ b, float* __restrict__ O, int n) {
  float wreg[64];
  const int t = threadIdx.x;
#pragma unroll
  for (int k = 0; k < 64; ++k) wreg[k] = W[k * HC + t];
  const float bias = b[t];
  __shared__ float arow[4][64];
  const int tr = t >> 6, tc = t & 63;
  for (int i0 = blockIdx.x * 4; i0 < n; i0 += gridDim.x * 4) {
    if (i0 + tr < n) arow[tr][tc] = A[(size_t)(i0 + tr) * 64 + tc];
    __syncthreads();
    float a0 = bias, a1 = bias, a2 = bias, a3 = bias;
#pragma unroll
    for (int k = 0; k < 64; ++k) {
      a0 = fmaf(arow[0][k], wreg[k], a0);
      a1 = fmaf(arow[1][k], wreg[k], a1);
      a2 = fmaf(arow[2][k], wreg[k], a2);
      a3 = fmaf(arow[3][k], wreg[k], a3);
    }
    if (i0 + 0 < n) O[(size_t)(i0 + 0) * HC + t] = a0;
    if (i0 + 1 < n) O[(size_t)(i0 + 1) * HC + t] = a1;
    if (i0 + 2 < n) O[(size_t)(i0 + 2) * HC + t] = a2;
    if (i0 + 3 < n) O[(size_t)(i0 + 3) * HC + t] = a3;
    __syncthreads();
  }
}

// Fused weights: Wc[k, j*4+h] = sum_c lin_w[k,h*64+c] * lo_w[h*64+c, j]; bc likewise from lin_b.
__global__ __launch_bounds__(256) void wc_kernel(
    const float* __restrict__ lin_w, const float* __restrict__ lin_b,
    const float* __restrict__ lo_w, float* __restrict__ Wc, float* __restrict__ bc) {
  const int t = threadIdx.x;
  const int j = t >> 2, h = t & 3;
  if (blockIdx.x < 64) {
    const int k = blockIdx.x;
    float acc = 0.f;
#pragma unroll 8
    for (int c = 0; c < 64; ++c)
      acc = fmaf(lin_w[k * HC + h * 64 + c], lo_w[(size_t)(h * 64 + c) * 64 + j], acc);
    Wc[k * HC + t] = acc;
  } else {
    float acc = 0.f;
#pragma unroll 8
    for (int c = 0; c < 64; ++c)
      acc = fmaf(lin_b[h * 64 + c], lo_w[(size_t)(h * 64 + c) * 64 + j], acc);
    bc[t] = acc;
  }
}

__global__ __launch_bounds__(256) void deg_kernel(const int* __restrict__ col,
                                                  int* __restrict__ deg, int E) {
  int e = blockIdx.x * blockDim.x + threadIdx.x;
  if (e < E) atomicAdd(&deg[col[e]], 1);
}

// single-block exclusive scan over deg -> offsets/cursor, plus dis = deg^-0.5
__global__ __launch_bounds__(256) void scan_kernel(
    const int* __restrict__ deg, int* __restrict__ offsets, int* __restrict__ cursor,
    float* __restrict__ dis, int n) {
  __shared__ int part[256];
  const int t = threadIdx.x;
  const int chunk = (n + 255) / 256;
  const int start = t * chunk;
  const int end = min(start + chunk, n);
  int s = 0;
  for (int i = start; i < end; ++i) s += deg[i];
  part[t] = s;
  __syncthreads();
  for (int off = 1; off < 256; off <<= 1) {
    int v = (t >= off) ? part[t - off] : 0;
    __syncthreads();
    part[t] += v;
    __syncthreads();
  }
  int run = (t == 0) ? 0 : part[t - 1];
  for (int i = start; i < end; ++i) {
    offsets[i] = run;
    cursor[i] = run;
    int d = deg[i];
    dis[i] = (d > 0) ? rsqrtf((float)d) : 0.f;
    run += d;
  }
  if (t == 255) offsets[n] = run;
}

// per-edge attention logits -> exp (max-shift dropped; shift-invariant) + segment sums
__global__ __launch_bounds__(256) void score_kernel(
    const int* __restrict__ row, const int* __restrict__ col,
    const float* __restrict__ xl, const float* __restrict__ xr,
    const float* __restrict__ att, float4* __restrict__ aexp,
    float* __restrict__ ssum, int E) {
  const int lane = threadIdx.x & 63;
  const int e = (int)(((size_t)blockIdx.x * blockDim.x + threadIdx.x) >> 6);
  if (e >= E) return;
  const int r = row[e], d = col[e];
  const float* pl = xl + (size_t)r * HC;
  const float* pr = xr + (size_t)d * HC;
  float s[4];
#pragma unroll
  for (int h = 0; h < 4; ++h) {
    float v = pl[h * 64 + lane] + pr[h * 64 + lane];
    v = (v > 0.f) ? v : 0.2f * v;
    s[h] = wave_sum(v * att[h * 64 + lane]);
  }
  if (lane == 0) {
    float4 a4 = {expf(s[0]), expf(s[1]), expf(s[2]), expf(s[3])};
    aexp[e] = a4;
    atomicAdd(&ssum[d * 4 + 0], a4.x);
    atomicAdd(&ssum[d * 4 + 1], a4.y);
    atomicAdd(&ssum[d * 4 + 2], a4.z);
    atomicAdd(&ssum[d * 4 + 3], a4.w);
  }
}

// normalize alpha, apply GCN norm, counting-sort edges into CSR by destination
__global__ __launch_bounds__(256) void scatter_kernel(
    const int* __restrict__ row, const int* __restrict__ col,
    const float4* __restrict__ aexp, const float* __restrict__ ssum,
    const float* __restrict__ dis, int* __restrict__ cursor,
    int* __restrict__ srow, float4* __restrict__ sw, int E) {
  int e = blockIdx.x * blockDim.x + threadIdx.x;
  if (e >= E) return;
  const int r = row[e], d = col[e];
  float4 a4 = aexp[e];
  const float norm = dis[r] * dis[d];
  float s0 = ssum[d * 4 + 0], s1 = ssum[d * 4 + 1], s2 = ssum[d * 4 + 2], s3 = ssum[d * 4 + 3];
  float4 w4;
  w4.x = a4.x / (s0 > 0.f ? s0 : 1.f) * norm;
  w4.y = a4.y / (s1 > 0.f ? s1 : 1.f) * norm;
  w4.z = a4.z / (s2 > 0.f ? s2 : 1.f) * norm;
  w4.w = a4.w / (s3 > 0.f ? s3 : 1.f) * norm;
  int pos = atomicAdd(&cursor[d], 1);
  srow[pos] = r;
  sw[pos] = w4;
}

// segmented aggregation (CSR) + oscillator update + rmsnorm, in-place on X,Y
__global__ __launch_bounds__(256) void layer_kernel(
    const int* __restrict__ offsets, const int* __restrict__ srow,
    const float4* __restrict__ sw, const float* __restrict__ M,
    const float* __restrict__ lo_b, float* __restrict__ X, float* __restrict__ Y,
    int n, float c_decay, float c_x, float c_k) {
  const int lane = threadIdx.x & 63;
  const int wid = (int)(((size_t)blockIdx.x * blockDim.x + threadIdx.x) >> 6);
  if (wid >= n) return;
  const int i = wid;
  const int s = offsets[i], e = offsets[i + 1];
  float acc = lo_b[lane];
  for (int p = s; p < e; ++p) {
    const int r = srow[p];
    const float4 w4 = sw[p];
    const float4 m4 = ((const float4*)(M + (size_t)r * HC))[lane];
    acc = fmaf(w4.x, m4.x, acc);
    acc = fmaf(w4.y, m4.y, acc);
    acc = fmaf(w4.z, m4.z, acc);
    acc = fmaf(w4.w, m4.w, acc);
  }
  const size_t idx = (size_t)i * 64 + lane;
  const float y = Y[idx], x = X[idx];
  const float yn = fmaf(c_k, acc, fmaf(c_x, x, c_decay * y));
  const float xn = fmaf(DT_F, yn, x);
  float sy = yn * yn, sx = xn * xn;
#pragma unroll
  for (int m = 32; m > 0; m >>= 1) {
    sy += __shfl_xor(sy, m);
    sx += __shfl_xor(sx, m);
  }
  Y[idx] = yn * rsqrtf(sy * (1.f / 64.f) + EPS_F);
  X[idx] = xn * rsqrtf(sx * (1.f / 64.f) + EPS_F);
}

// out[n,16] = X[n,64] @ dec_w[64,16] + dec_b
__global__ __launch_bounds__(256) void dec_kernel(
    const float* __restrict__ X, const float* __restrict__ w,
    const float* __restrict__ b, float* __restrict__ out, int n) {
  __shared__ float ws[64 * NCLS];
  for (int t = threadIdx.x; t < 64 * NCLS; t += blockDim.x) ws[t] = w[t];
  __syncthreads();
  const int t = threadIdx.x;
  const int jr = t & 15, ir = t >> 4;  // 16 rows / block
  for (int i0 = blockIdx.x * 16; i0 < n; i0 += gridDim.x * 16) {
    const int i = i0 + ir;
    if (i < n) {
      const float* xrow = X + (size_t)i * 64;
      float acc = b[jr];
#pragma unroll 8
      for (int k = 0; k < 64; ++k) acc = fmaf(xrow[k], ws[k * NCLS + jr], acc);
      out[(size_t)i * NCLS + jr] = acc;
    }
  }
}

static inline size_t alignup(size_t x) { return (x + 255) & ~(size_t)255; }

extern "C" void kernel_launch(void* const* d_in, const int* in_sizes, int n_in,
                              void* d_out, int out_size, void* d_ws, size_t ws_size,
                              hipStream_t stream) {
  const float* x     = (const float*)d_in[0];
  const float* enc_w = (const float*)d_in[1];
  const float* enc_b = (const float*)d_in[2];
  const float* dec_w = (const float*)d_in[3];
  const float* dec_b = (const float*)d_in[4];
  const float* lo_w  = (const float*)d_in[5];
  const float* lo_b  = (const float*)d_in[6];
  const float* dpl_w = (const float*)d_in[7];
  const float* dpl_b = (const float*)d_in[8];
  const float* dpr_w = (const float*)d_in[9];
  const float* dpr_b = (const float*)d_in[10];
  const float* lin_w = (const float*)d_in[11];
  const float* lin_b = (const float*)d_in[12];
  const float* att   = (const float*)d_in[13];
  const int*   ei    = (const int*)d_in[14];

  const int n = in_sizes[0] / NFEAT;
  const int E = in_sizes[14] / 2;
  const int* row = ei;
  const int* col = ei + E;

  // workspace carve-up
  char* p = (char*)d_ws;
  size_t off = 0;
  auto alloc = [&](size_t bytes) { void* r = p + off; off += alignup(bytes); return r; };
  float* Y    = (float*)alloc((size_t)n * 64 * 4);
  float* X    = (float*)alloc((size_t)n * 64 * 4);
  float* xl   = (float*)alloc((size_t)n * HC * 4);  // reused as M in the layer loop
  float* xr   = (float*)alloc((size_t)n * HC * 4);
  float4* aexp = (float4*)alloc((size_t)E * 16);
  float4* sw   = (float4*)alloc((size_t)E * 16);
  int*   srow = (int*)alloc((size_t)E * 4);
  int*   deg  = (int*)alloc((size_t)n * 4);
  int*   offs = (int*)alloc((size_t)(n + 1) * 4);
  int*   cur  = (int*)alloc((size_t)n * 4);
  float* dis  = (float*)alloc((size_t)n * 4);
  float* ssum = (float*)alloc((size_t)n * 4 * 4);
  float* Wc   = (float*)alloc((size_t)64 * HC * 4);
  float* bc   = (float*)alloc((size_t)HC * 4);
  float* M = xl;  // overlay: xl dead after score_kernel

  // dynamics constants (softplus(1) in double, then fold into update coefficients)
  const double sp = log1p(exp(1.0));  // omega = zeta = Ks
  const float c_decay = (float)(1.0 - 2.0 * sp * sp * 0.01);
  const float c_x     = (float)(-(sp * sp) * 0.01);
  const float c_k     = (float)(sp * 0.01);

  hipMemsetAsync(deg, 0, (size_t)n * 4, stream);
  hipMemsetAsync(ssum, 0, (size_t)n * 16, stream);

  const int nodeBlocks = (n + 3) / 4;       // 1 wave per node, 4 waves/block
  enc_kernel<<<nodeBlocks, 256, 0, stream>>>(x, enc_w, enc_b, Y, X, n);
  rowgemm64_256<<<512, 256, 0, stream>>>(Y, dpl_w, dpl_b, xl, n);
  rowgemm64_256<<<512, 256, 0, stream>>>(Y, dpr_w, dpr_b, xr, n);
  wc_kernel<<<65, 256, 0, stream>>>(lin_w, lin_b, lo_w, Wc, bc);
  deg_kernel<<<(E + 255) / 256, 256, 0, stream>>>(col, deg, E);
  scan_kernel<<<1, 256, 0, stream>>>(deg, offs, cur, dis, n);
  score_kernel<<<(E + 3) / 4, 256, 0, stream>>>(row, col, xl, xr, att, aexp, ssum, E);
  scatter_kernel<<<(E + 255) / 256, 256, 0, stream>>>(row, col, aexp, ssum, dis, cur,
                                                      srow, sw, E);
  for (int l = 0; l < 4; ++l) {
    rowgemm64_256<<<512, 256, 0, stream>>>(Y, Wc, bc, M, n);
    layer_kernel<<<nodeBlocks, 256, 0, stream>>>(offs, srow, sw, M, lo_b, X, Y, n,
                                                 c_decay, c_x, c_k);
  }
  dec_kernel<<<(n + 15) / 16, 256, 0, stream>>>(X, dec_w, dec_b, (float*)d_out, n);
}

// Round 2
// 392.022 us; speedup vs baseline: 1.0430x; 1.0430x over previous
//
#include <hip/hip_runtime.h>
#include <math.h>

#define NFEAT 128
#define NHID  64
#define HC    256   // HEADS*NHID
#define NCLS  16
#define DT_F  0.01f
#define EPS_F 1e-5f

// Y = relu(x @ enc_w + enc_b); X = Y.   x:[n,128] w:[128,64]
__global__ __launch_bounds__(256) void enc_kernel(
    const float* __restrict__ x, const float* __restrict__ w,
    const float* __restrict__ b, float* __restrict__ Y, float* __restrict__ X, int n) {
  __shared__ float ws[NFEAT * NHID];  // 32KB
  for (int t = threadIdx.x; t < NFEAT * NHID; t += blockDim.x) ws[t] = w[t];
  __syncthreads();
  const int wave = threadIdx.x >> 6, lane = threadIdx.x & 63;
  for (int i = blockIdx.x * 4 + wave; i < n; i += gridDim.x * 4) {
    const float* xr = x + (size_t)i * NFEAT;
    float acc = b[lane];
#pragma unroll 8
    for (int k = 0; k < NFEAT; ++k) acc = fmaf(xr[k], ws[k * NHID + lane], acc);
    acc = fmaxf(acc, 0.f);
    Y[(size_t)i * NHID + lane] = acc;
    X[(size_t)i * NHID + lane] = acc;
  }
}

// O[n,256] = A[n,64] @ W[64,256] + b  (weights in registers, rows staged in LDS)
__global__ __launch_bounds__(256) void rowgemm64_256(
    const float* __restrict__ A, const float* __restrict__ W,
    const float* __restrict__ b, float* __restrict__ O, int n) {
  float wreg[64];
  const int t = threadIdx.x;
#pragma unroll
  for (int k = 0; k < 64; ++k) wreg[k] = W[k * HC + t];
  const float bias = b[t];
  __shared__ float arow[4][64];
  const int tr = t >> 6, tc = t & 63;
  for (int i0 = blockIdx.x * 4; i0 < n; i0 += gridDim.x * 4) {
    if (i0 + tr < n) arow[tr][tc] = A[(size_t)(i0 + tr) * 64 + tc];
    __syncthreads();
    float a0 = bias, a1 = bias, a2 = bias, a3 = bias;
#pragma unroll
    for (int k = 0; k < 64; ++k) {
      a0 = fmaf(arow[0][k], wreg[k], a0);
      a1 = fmaf(arow[1][k], wreg[k], a1);
      a2 = fmaf(arow[2][k], wreg[k], a2);
      a3 = fmaf(arow[3][k], wreg[k], a3);
    }
    if (i0 + 0 < n) O[(size_t)(i0 + 0) * HC + t] = a0;
    if (i0 + 1 < n) O[(size_t)(i0 + 1) * HC + t] = a1;
    if (i0 + 2 < n) O[(size_t)(i0 + 2) * HC + t] = a2;
    if (i0 + 3 < n) O[(size_t)(i0 + 3) * HC + t] = a3;
    __syncthreads();
  }
}

// Wc2[(h*64+k)*64 + j] = sum_c lin_w[k, h*64+c] * lo_w[h*64+c, j]
// bb[h*64+j]           = sum_c lin_b[h*64+c]    * lo_w[h*64+c, j]
__global__ __launch_bounds__(64) void wc2_kernel(
    const float* __restrict__ lin_w, const float* __restrict__ lin_b,
    const float* __restrict__ lo_w, float* __restrict__ Wc2, float* __restrict__ bb) {
  const int j = threadIdx.x;
  const int b = blockIdx.x;
  if (b < 256) {
    const int h = b >> 6, k = b & 63;
    float acc = 0.f;
#pragma unroll 8
    for (int c = 0; c < 64; ++c)
      acc = fmaf(lin_w[k * HC + h * 64 + c], lo_w[(size_t)(h * 64 + c) * 64 + j], acc);
    Wc2[b * 64 + j] = acc;
  } else {
    const int h = b - 256;
    float acc = 0.f;
#pragma unroll 8
    for (int c = 0; c < 64; ++c)
      acc = fmaf(lin_b[h * 64 + c], lo_w[(size_t)(h * 64 + c) * 64 + j], acc);
    bb[h * 64 + j] = acc;
  }
}

__global__ __launch_bounds__(256) void deg_kernel(const int* __restrict__ col,
                                                  int* __restrict__ deg, int E) {
  int e = blockIdx.x * blockDim.x + threadIdx.x;
  if (e < E) atomicAdd(&deg[col[e]], 1);
}

// single-block exclusive scan over deg -> offsets/cursor, plus dis = deg^-0.5
__global__ __launch_bounds__(256) void scan_kernel(
    const int* __restrict__ deg, int* __restrict__ offsets, int* __restrict__ cursor,
    float* __restrict__ dis, int n) {
  __shared__ int part[256];
  const int t = threadIdx.x;
  const int chunk = (n + 255) / 256;
  const int start = t * chunk;
  const int end = min(start + chunk, n);
  int s = 0;
  for (int i = start; i < end; ++i) s += deg[i];
  part[t] = s;
  __syncthreads();
  for (int off = 1; off < 256; off <<= 1) {
    int v = (t >= off) ? part[t - off] : 0;
    __syncthreads();
    part[t] += v;
    __syncthreads();
  }
  int run = (t == 0) ? 0 : part[t - 1];
  for (int i = start; i < end; ++i) {
    offsets[i] = run;
    cursor[i] = run;
    int d = deg[i];
    dis[i] = (d > 0) ? rsqrtf((float)d) : 0.f;
    run += d;
  }
  if (t == 255) offsets[n] = run;
}

// counting-sort src indices into CSR order by destination
__global__ __launch_bounds__(256) void scatter_kernel(
    const int* __restrict__ row, const int* __restrict__ col,
    int* __restrict__ cursor, int* __restrict__ srow, int E) {
  int e = blockIdx.x * blockDim.x + threadIdx.x;
  if (e >= E) return;
  int pos = atomicAdd(&cursor[col[e]], 1);
  srow[pos] = row[e];
}

// Per dst node (one wave, CSR order): edge attention logits -> exp, store
// a*dis[r] per edge; per-node inverse softmax-sum * dis[d] -> invq.
// Lane L covers flat channels L*4..L*4+3 (head h = L>>4) via one float4.
__global__ __launch_bounds__(256) void score_kernel(
    const int* __restrict__ offs, const int* __restrict__ srow,
    const float4* __restrict__ xl4, const float4* __restrict__ xr4,
    const float* __restrict__ att, const float* __restrict__ dis,
    float4* __restrict__ sw, float4* __restrict__ invq, int n) {
  const int wave = threadIdx.x >> 6, lane = threadIdx.x & 63;
  const float4 at4 = ((const float4*)att)[lane];
  const int d = blockIdx.x * 4 + wave;
  if (d >= n) return;
  const int s = offs[d], e = offs[d + 1];
  if (s >= e) return;
  const float4 r4 = xr4[(size_t)d * 64 + lane];
  const float dd = dis[d];
  float ssum = 0.f;
  for (int p = s; p < e; ++p) {
    const int r = srow[p];
    const float4 l4 = xl4[(size_t)r * 64 + lane];
    float vx = l4.x + r4.x, vy = l4.y + r4.y, vz = l4.z + r4.z, vw = l4.w + r4.w;
    vx = fmaxf(vx, 0.2f * vx); vy = fmaxf(vy, 0.2f * vy);
    vz = fmaxf(vz, 0.2f * vz); vw = fmaxf(vw, 0.2f * vw);
    float pt = vx * at4.x;
    pt = fmaf(vy, at4.y, pt);
    pt = fmaf(vz, at4.z, pt);
    pt = fmaf(vw, at4.w, pt);
#pragma unroll
    for (int m = 1; m < 16; m <<= 1) pt += __shfl_xor(pt, m);
    const float a = expf(pt);      // max-shift dropped: shift-invariant, scores O(1)
    ssum += a;
    const float as = a * dis[r];
    // lanes 0,16,32,48 write the 4 head components (contiguous 16B)
    if ((lane & 15) == 0) ((float*)&sw[p])[lane >> 4] = as;
  }
  const float inv = dd / (ssum > 0.f ? ssum : 1.f);
  if ((lane & 15) == 0) ((float*)&invq[d])[lane >> 4] = inv;
}

// Fused per layer: CSR-aggregate Y (weighted per head) -> in-LDS GEMM vs Wc2
// -> oscillator update -> rmsnorm. Reads Yin, writes Yout (ping-pong), X in place.
__global__ __launch_bounds__(256) void layer_kernel(
    const int* __restrict__ offs, const int* __restrict__ srow,
    const float4* __restrict__ sw, const float4* __restrict__ invq,
    const float* __restrict__ Wc2, const float* __restrict__ bb,
    const float* __restrict__ lo_b, const float* __restrict__ Yin,
    float* __restrict__ Yout, float* __restrict__ X, int n,
    float c_decay, float c_x, float c_k) {
  __shared__ float wlds[HC * 64];   // 64KB: Wc2[hk][j]
  __shared__ float alds[4][HC];     // per-wave agg staging
  for (int t = threadIdx.x; t < HC * 64; t += 256) wlds[t] = Wc2[t];
  __syncthreads();
  const int wave = threadIdx.x >> 6, lane = threadIdx.x & 63;
  const float bias = lo_b[lane];
  const float bb0 = bb[lane], bb1 = bb[64 + lane], bb2 = bb[128 + lane], bb3 = bb[192 + lane];
  for (int i = blockIdx.x * 4 + wave; i < n; i += gridDim.x * 4) {
    const int s = offs[i], e = offs[i + 1];
    const float4 iv = invq[i];      // dead if s==e
    float a0 = 0.f, a1 = 0.f, a2 = 0.f, a3 = 0.f;
    float w0 = 0.f, w1 = 0.f, w2 = 0.f, w3 = 0.f;
    for (int p = s; p < e; ++p) {
      const int r = srow[p];
      float4 wv = sw[p];
      wv.x *= iv.x; wv.y *= iv.y; wv.z *= iv.z; wv.w *= iv.w;
      const float yv = Yin[(size_t)r * 64 + lane];
      a0 = fmaf(wv.x, yv, a0); a1 = fmaf(wv.y, yv, a1);
      a2 = fmaf(wv.z, yv, a2); a3 = fmaf(wv.w, yv, a3);
      w0 += wv.x; w1 += wv.y; w2 += wv.z; w3 += wv.w;
    }
    // stage agg (lane = channel k, 4 heads) for the cross-lane GEMM
    alds[wave][lane] = a0;
    alds[wave][64 + lane] = a1;
    alds[wave][128 + lane] = a2;
    alds[wave][192 + lane] = a3;
    float out = bias;
    out = fmaf(w0, bb0, out); out = fmaf(w1, bb1, out);
    out = fmaf(w2, bb2, out); out = fmaf(w3, bb3, out);
    // same-wave LDS write->read: compiler inserts lgkmcnt; no barrier needed
#pragma unroll 4
    for (int hk = 0; hk < HC; hk += 4) {
      const float4 av = *reinterpret_cast<const float4*>(&alds[wave][hk]);  // broadcast
      out = fmaf(av.x, wlds[(hk + 0) * 64 + lane], out);
      out = fmaf(av.y, wlds[(hk + 1) * 64 + lane], out);
      out = fmaf(av.z, wlds[(hk + 2) * 64 + lane], out);
      out = fmaf(av.w, wlds[(hk + 3) * 64 + lane], out);
    }
    const size_t idx = (size_t)i * 64 + lane;
    const float y = Yin[idx], x = X[idx];
    const float yn = fmaf(c_k, out, fmaf(c_x, x, c_decay * y));
    const float xn = fmaf(DT_F, yn, x);
    float sy = yn * yn, sx = xn * xn;
#pragma unroll
    for (int m = 32; m > 0; m >>= 1) {
      sy += __shfl_xor(sy, m);
      sx += __shfl_xor(sx, m);
    }
    Yout[idx] = yn * rsqrtf(sy * (1.f / 64.f) + EPS_F);
    X[idx]    = xn * rsqrtf(sx * (1.f / 64.f) + EPS_F);
  }
}

// out[n,16] = X[n,64] @ dec_w[64,16] + dec_b
__global__ __launch_bounds__(256) void dec_kernel(
    const float* __restrict__ X, const float* __restrict__ w,
    const float* __restrict__ b, float* __restrict__ out, int n) {
  __shared__ float ws[64 * NCLS];
  for (int t = threadIdx.x; t < 64 * NCLS; t += blockDim.x) ws[t] = w[t];
  __syncthreads();
  const int t = threadIdx.x;
  const int jr = t & 15, ir = t >> 4;  // 16 rows / block
  for (int i0 = blockIdx.x * 16; i0 < n; i0 += gridDim.x * 16) {
    const int i = i0 + ir;
    if (i < n) {
      const float* xrow = X + (size_t)i * 64;
      float acc = b[jr];
#pragma unroll 8
      for (int k = 0; k < 64; ++k) acc = fmaf(xrow[k], ws[k * NCLS + jr], acc);
      out[(size_t)i * NCLS + jr] = acc;
    }
  }
}

static inline size_t alignup(size_t x) { return (x + 255) & ~(size_t)255; }

extern "C" void kernel_launch(void* const* d_in, const int* in_sizes, int n_in,
                              void* d_out, int out_size, void* d_ws, size_t ws_size,
                              hipStream_t stream) {
  const float* x     = (const float*)d_in[0];
  const float* enc_w = (const float*)d_in[1];
  const float* enc_b = (const float*)d_in[2];
  const float* dec_w = (const float*)d_in[3];
  const float* dec_b = (const float*)d_in[4];
  const float* lo_w  = (const float*)d_in[5];
  const float* lo_b  = (const float*)d_in[6];
  const float* dpl_w = (const float*)d_in[7];
  const float* dpl_b = (const float*)d_in[8];
  const float* dpr_w = (const float*)d_in[9];
  const float* dpr_b = (const float*)d_in[10];
  const float* lin_w = (const float*)d_in[11];
  const float* lin_b = (const float*)d_in[12];
  const float* att   = (const float*)d_in[13];
  const int*   ei    = (const int*)d_in[14];

  const int n = in_sizes[0] / NFEAT;
  const int E = in_sizes[14] / 2;
  const int* row = ei;
  const int* col = ei + E;

  // workspace carve-up
  char* p = (char*)d_ws;
  size_t off = 0;
  auto alloc = [&](size_t bytes) { void* r = p + off; off += alignup(bytes); return r; };
  float*  Y    = (float*)alloc((size_t)n * 64 * 4);
  float*  Y2   = (float*)alloc((size_t)n * 64 * 4);
  float*  X    = (float*)alloc((size_t)n * 64 * 4);
  float*  xl   = (float*)alloc((size_t)n * HC * 4);
  float*  xr   = (float*)alloc((size_t)n * HC * 4);
  float4* sw   = (float4*)alloc((size_t)E * 16);
  int*    srow = (int*)alloc((size_t)E * 4);
  int*    deg  = (int*)alloc((size_t)n * 4);
  int*    offs = (int*)alloc((size_t)(n + 1) * 4);
  int*    cur  = (int*)alloc((size_t)n * 4);
  float*  dis  = (float*)alloc((size_t)n * 4);
  float4* invq = (float4*)alloc((size_t)n * 16);
  float*  Wc2  = (float*)alloc((size_t)HC * 64 * 4);
  float*  bb   = (float*)alloc((size_t)HC * 4);

  // dynamics constants (softplus(1) in double, folded into update coefficients)
  const double sp = log1p(exp(1.0));  // omega = zeta = Ks
  const float c_decay = (float)(1.0 - 2.0 * sp * sp * 0.01);
  const float c_x     = (float)(-(sp * sp) * 0.01);
  const float c_k     = (float)(sp * 0.01);

  hipMemsetAsync(deg, 0, (size_t)n * 4, stream);

  enc_kernel<<<512, 256, 0, stream>>>(x, enc_w, enc_b, Y, X, n);
  rowgemm64_256<<<512, 256, 0, stream>>>(Y, dpl_w, dpl_b, xl, n);
  rowgemm64_256<<<512, 256, 0, stream>>>(Y, dpr_w, dpr_b, xr, n);
  wc2_kernel<<<260, 64, 0, stream>>>(lin_w, lin_b, lo_w, Wc2, bb);
  deg_kernel<<<(E + 255) / 256, 256, 0, stream>>>(col, deg, E);
  scan_kernel<<<1, 256, 0, stream>>>(deg, offs, cur, dis, n);
  scatter_kernel<<<(E + 255) / 256, 256, 0, stream>>>(row, col, cur, srow, E);
  score_kernel<<<(n + 3) / 4, 256, 0, stream>>>(offs, srow, (const float4*)xl,
                                                (const float4*)xr, att, dis, sw, invq, n);
  const float* Yin = Y;
  float* Yout = Y2;
  for (int l = 0; l < 4; ++l) {
    layer_kernel<<<512, 256, 0, stream>>>(offs, srow, sw, invq, Wc2, bb, lo_b,
                                          Yin, Yout, X, n, c_decay, c_x, c_k);
    const float* tmp = Yout; Yout = (float*)Yin; Yin = tmp;
  }
  dec_kernel<<<(n + 15) / 16, 256, 0, stream>>>(X, dec_w, dec_b, (float*)d_out, n);
}

// Round 3
// 326.085 us; speedup vs baseline: 1.2539x; 1.2022x over previous
//
#include <hip/hip_runtime.h>
#include <math.h>

#define NFEAT 128
#define NHID  64
#define HC    256   // HEADS*NHID
#define NCLS  16
#define DT_F  0.01f
#define EPS_F 1e-5f

// Y = relu(x @ enc_w + enc_b); X = Y.   x:[n,128] w:[128,64]
__global__ __launch_bounds__(256) void enc_kernel(
    const float* __restrict__ x, const float* __restrict__ w,
    const float* __restrict__ b, float* __restrict__ Y, float* __restrict__ X, int n) {
  __shared__ float ws[NFEAT * NHID];  // 32KB
  for (int t = threadIdx.x; t < NFEAT * NHID; t += blockDim.x) ws[t] = w[t];
  __syncthreads();
  const int wave = threadIdx.x >> 6, lane = threadIdx.x & 63;
  for (int i = blockIdx.x * 4 + wave; i < n; i += gridDim.x * 4) {
    const float* xr = x + (size_t)i * NFEAT;
    float acc = b[lane];
#pragma unroll 8
    for (int k = 0; k < NFEAT; ++k) acc = fmaf(xr[k], ws[k * NHID + lane], acc);
    acc = fmaxf(acc, 0.f);
    Y[(size_t)i * NHID + lane] = acc;
    X[(size_t)i * NHID + lane] = acc;
  }
}

// O[n,256] = A[n,64] @ W[64,256] + b. Weights in registers; A rows read with
// wave-uniform addresses (scalar loads), no LDS.
__global__ __launch_bounds__(256) void rowgemm64_256(
    const float* __restrict__ A, const float* __restrict__ W,
    const float* __restrict__ b, float* __restrict__ O, int n) {
  float wreg[64];
  const int t = threadIdx.x;
#pragma unroll
  for (int k = 0; k < 64; ++k) wreg[k] = W[k * HC + t];
  const float bias = b[t];
  for (int i0 = blockIdx.x * 4; i0 < n; i0 += gridDim.x * 4) {
    const float* ap = A + (size_t)i0 * 64;
    float a0 = bias, a1 = bias, a2 = bias, a3 = bias;
#pragma unroll
    for (int k = 0; k < 64; ++k) {
      const float w = wreg[k];
      a0 = fmaf(ap[k], w, a0);
      a1 = fmaf(ap[64 + k], w, a1);
      a2 = fmaf(ap[128 + k], w, a2);
      a3 = fmaf(ap[192 + k], w, a3);
    }
    if (i0 + 0 < n) O[(size_t)(i0 + 0) * HC + t] = a0;
    if (i0 + 1 < n) O[(size_t)(i0 + 1) * HC + t] = a1;
    if (i0 + 2 < n) O[(size_t)(i0 + 2) * HC + t] = a2;
    if (i0 + 3 < n) O[(size_t)(i0 + 3) * HC + t] = a3;
  }
}

// Wext[(k*4+h)*64 + j] = sum_c lin_w[k, h*64+c] * lo_w[h*64+c, j]   (b in 0..255)
// bb[h*64+j]           = sum_c lin_b[h*64+c]    * lo_w[h*64+c, j]   (b in 256..259)
__global__ __launch_bounds__(64) void wext_kernel(
    const float* __restrict__ lin_w, const float* __restrict__ lin_b,
    const float* __restrict__ lo_w, float* __restrict__ Wext, float* __restrict__ bb) {
  const int j = threadIdx.x;
  const int b = blockIdx.x;
  if (b < 256) {
    const int k = b >> 2, h = b & 3;
    float acc = 0.f;
#pragma unroll 8
    for (int c = 0; c < 64; ++c)
      acc = fmaf(lin_w[k * HC + h * 64 + c], lo_w[(size_t)(h * 64 + c) * 64 + j], acc);
    Wext[b * 64 + j] = acc;
  } else {
    const int h = b - 256;
    float acc = 0.f;
#pragma unroll 8
    for (int c = 0; c < 64; ++c)
      acc = fmaf(lin_b[h * 64 + c], lo_w[(size_t)(h * 64 + c) * 64 + j], acc);
    bb[h * 64 + j] = acc;
  }
}

__global__ __launch_bounds__(256) void deg_kernel(const int* __restrict__ col,
                                                  int* __restrict__ deg, int E) {
  int e = blockIdx.x * blockDim.x + threadIdx.x;
  if (e < E) atomicAdd(&deg[col[e]], 1);
}

// single-block exclusive scan over deg -> offsets/cursor, dis = deg^-0.5,
// and zero-init invq/wq for isolated nodes (score skips them).
__global__ __launch_bounds__(256) void scan_kernel(
    const int* __restrict__ deg, int* __restrict__ offsets, int* __restrict__ cursor,
    float* __restrict__ dis, float4* __restrict__ invq, float4* __restrict__ wq, int n) {
  __shared__ int part[256];
  const int t = threadIdx.x;
  const int chunk = (n + 255) / 256;
  const int start = t * chunk;
  const int end = min(start + chunk, n);
  int s = 0;
  for (int i = start; i < end; ++i) s += deg[i];
  part[t] = s;
  __syncthreads();
  for (int off = 1; off < 256; off <<= 1) {
    int v = (t >= off) ? part[t - off] : 0;
    __syncthreads();
    part[t] += v;
    __syncthreads();
  }
  int run = (t == 0) ? 0 : part[t - 1];
  for (int i = start; i < end; ++i) {
    offsets[i] = run;
    cursor[i] = run;
    int d = deg[i];
    dis[i] = (d > 0) ? rsqrtf((float)d) : 0.f;
    if (d == 0) {
      invq[i] = make_float4(0.f, 0.f, 0.f, 0.f);
      wq[i] = make_float4(0.f, 0.f, 0.f, 0.f);
    }
    run += d;
  }
  if (t == 255) offsets[n] = run;
}

// counting-sort src indices into CSR order by destination
__global__ __launch_bounds__(256) void scatter_kernel(
    const int* __restrict__ row, const int* __restrict__ col,
    int* __restrict__ cursor, int* __restrict__ srow, int E) {
  int e = blockIdx.x * blockDim.x + threadIdx.x;
  if (e >= E) return;
  int pos = atomicAdd(&cursor[col[e]], 1);
  srow[pos] = row[e];
}

// Per dst node (one wave, CSR order): exp(logit)*dis[r] per edge -> sw;
// per-node invq = dis[d]/ssum and wq = (sum_e a*dis[r]) * invq (per head).
// Lane L covers flat channels L*4..L*4+3 (head h = L>>4) via one float4.
__global__ __launch_bounds__(256) void score_kernel(
    const int* __restrict__ offs, const int* __restrict__ srow,
    const float4* __restrict__ xl4, const float4* __restrict__ xr4,
    const float* __restrict__ att, const float* __restrict__ dis,
    float4* __restrict__ sw, float4* __restrict__ invq, float4* __restrict__ wq, int n) {
  const int wave = threadIdx.x >> 6, lane = threadIdx.x & 63;
  const int d = blockIdx.x * 4 + wave;
  if (d >= n) return;
  const int s = offs[d], e = offs[d + 1];
  if (s >= e) return;  // scan pre-zeroed invq/wq
  const float4 at4 = ((const float4*)att)[lane];
  const float4 r4 = xr4[(size_t)d * 64 + lane];
  const float dd = dis[d];
  float ssum = 0.f, wsum = 0.f;
  int p = s;
  for (; p + 1 < e; p += 2) {
    const int r0 = srow[p], r1 = srow[p + 1];
    const float4 l0 = xl4[(size_t)r0 * 64 + lane];
    const float4 l1 = xl4[(size_t)r1 * 64 + lane];
    const float di0 = dis[r0], di1 = dis[r1];
    float vx = l0.x + r4.x, vy = l0.y + r4.y, vz = l0.z + r4.z, vw = l0.w + r4.w;
    vx = fmaxf(vx, 0.2f * vx); vy = fmaxf(vy, 0.2f * vy);
    vz = fmaxf(vz, 0.2f * vz); vw = fmaxf(vw, 0.2f * vw);
    float t0 = vx * at4.x;
    t0 = fmaf(vy, at4.y, t0); t0 = fmaf(vz, at4.z, t0); t0 = fmaf(vw, at4.w, t0);
    vx = l1.x + r4.x; vy = l1.y + r4.y; vz = l1.z + r4.z; vw = l1.w + r4.w;
    vx = fmaxf(vx, 0.2f * vx); vy = fmaxf(vy, 0.2f * vy);
    vz = fmaxf(vz, 0.2f * vz); vw = fmaxf(vw, 0.2f * vw);
    float t1 = vx * at4.x;
    t1 = fmaf(vy, at4.y, t1); t1 = fmaf(vz, at4.z, t1); t1 = fmaf(vw, at4.w, t1);
#pragma unroll
    for (int m = 1; m < 16; m <<= 1) {
      t0 += __shfl_xor(t0, m);
      t1 += __shfl_xor(t1, m);
    }
    const float a0 = __expf(t0), a1 = __expf(t1);
    ssum += a0 + a1;
    const float s0 = a0 * di0, s1 = a1 * di1;
    wsum += s0 + s1;
    if ((lane & 15) == 0) {
      ((float*)&sw[p])[lane >> 4] = s0;
      ((float*)&sw[p + 1])[lane >> 4] = s1;
    }
  }
  for (; p < e; ++p) {
    const int r0 = srow[p];
    const float4 l0 = xl4[(size_t)r0 * 64 + lane];
    const float di0 = dis[r0];
    float vx = l0.x + r4.x, vy = l0.y + r4.y, vz = l0.z + r4.z, vw = l0.w + r4.w;
    vx = fmaxf(vx, 0.2f * vx); vy = fmaxf(vy, 0.2f * vy);
    vz = fmaxf(vz, 0.2f * vz); vw = fmaxf(vw, 0.2f * vw);
    float t0 = vx * at4.x;
    t0 = fmaf(vy, at4.y, t0); t0 = fmaf(vz, at4.z, t0); t0 = fmaf(vw, at4.w, t0);
#pragma unroll
    for (int m = 1; m < 16; m <<= 1) t0 += __shfl_xor(t0, m);
    const float a0 = __expf(t0);
    ssum += a0;
    const float s0 = a0 * di0;
    wsum += s0;
    if ((lane & 15) == 0) ((float*)&sw[p])[lane >> 4] = s0;
  }
  const float inv = dd / (ssum > 0.f ? ssum : 1.f);
  if ((lane & 15) == 0) {
    ((float*)&invq[d])[lane >> 4] = inv;
    ((float*)&wq[d])[lane >> 4] = wsum * inv;
  }
}

// fb[i][j] = lo_b[j] + sum_h wq[i].h * bb[h*64+j]   (layer-invariant bias)
__global__ __launch_bounds__(256) void fb_kernel(
    const float4* __restrict__ wq, const float* __restrict__ bb,
    const float* __restrict__ lo_b, float* __restrict__ fb, int n) {
  const int wave = threadIdx.x >> 6, lane = threadIdx.x & 63;
  const int i = blockIdx.x * 4 + wave;
  if (i >= n) return;
  const float4 w = wq[i];
  float v = lo_b[lane];
  v = fmaf(w.x, bb[lane], v);
  v = fmaf(w.y, bb[64 + lane], v);
  v = fmaf(w.z, bb[128 + lane], v);
  v = fmaf(w.w, bb[192 + lane], v);
  fb[(size_t)i * 64 + lane] = v;
}

// Per-node (one wave) CSR gather: agg[i][k*4+h] = invq.h * sum_e sw[e].h * Y[r][k]
// Edge loop unrolled x4 for memory-level parallelism. No LDS -> full occupancy.
__global__ __launch_bounds__(256) void agg_kernel(
    const int* __restrict__ offs, const int* __restrict__ srow,
    const float4* __restrict__ sw, const float4* __restrict__ invq,
    const float* __restrict__ Yin, float* __restrict__ agg, int n) {
  const int wave = threadIdx.x >> 6, lane = threadIdx.x & 63;
  const int i = blockIdx.x * 4 + wave;
  if (i >= n) return;
  const int s = offs[i], e = offs[i + 1];
  float a0 = 0.f, a1 = 0.f, a2 = 0.f, a3 = 0.f;
  int p = s;
  for (; p + 3 < e; p += 4) {
    const int r0 = srow[p], r1 = srow[p + 1], r2 = srow[p + 2], r3 = srow[p + 3];
    const float4 v0 = sw[p], v1 = sw[p + 1], v2 = sw[p + 2], v3 = sw[p + 3];
    const float y0 = Yin[(size_t)r0 * 64 + lane];
    const float y1 = Yin[(size_t)r1 * 64 + lane];
    const float y2 = Yin[(size_t)r2 * 64 + lane];
    const float y3 = Yin[(size_t)r3 * 64 + lane];
    a0 = fmaf(v0.x, y0, a0); a1 = fmaf(v0.y, y0, a1);
    a2 = fmaf(v0.z, y0, a2); a3 = fmaf(v0.w, y0, a3);
    a0 = fmaf(v1.x, y1, a0); a1 = fmaf(v1.y, y1, a1);
    a2 = fmaf(v1.z, y1, a2); a3 = fmaf(v1.w, y1, a3);
    a0 = fmaf(v2.x, y2, a0); a1 = fmaf(v2.y, y2, a1);
    a2 = fmaf(v2.z, y2, a2); a3 = fmaf(v2.w, y2, a3);
    a0 = fmaf(v3.x, y3, a0); a1 = fmaf(v3.y, y3, a1);
    a2 = fmaf(v3.z, y3, a2); a3 = fmaf(v3.w, y3, a3);
  }
  for (; p < e; ++p) {
    const int r0 = srow[p];
    const float4 v0 = sw[p];
    const float y0 = Yin[(size_t)r0 * 64 + lane];
    a0 = fmaf(v0.x, y0, a0); a1 = fmaf(v0.y, y0, a1);
    a2 = fmaf(v0.z, y0, a2); a3 = fmaf(v0.w, y0, a3);
  }
  const float4 iv = invq[i];
  float4 o;
  o.x = a0 * iv.x; o.y = a1 * iv.y; o.z = a2 * iv.z; o.w = a3 * iv.w;
  ((float4*)(agg + (size_t)i * 256))[lane] = o;
}

// out[i][j] = fb[i][j] + sum_{flat=0..255} agg[i][flat] * Wext[flat][j], then
// oscillator update + rmsnorm. Wext in registers partitioned across 4 waves;
// agg rows read with wave-uniform addresses (scalar loads). 4 nodes per round.
__global__ __launch_bounds__(256) void gemmupd_kernel(
    const float* __restrict__ agg, const float* __restrict__ Wext,
    const float* __restrict__ fb, const float* __restrict__ Yin,
    float* __restrict__ Yout, float* __restrict__ X, int n,
    float c_decay, float c_x, float c_k) {
  const int t = threadIdx.x, tr = t >> 6, j = t & 63;
  float wreg[64];
#pragma unroll
  for (int q = 0; q < 64; ++q) wreg[q] = Wext[(tr * 64 + q) * 64 + j];
  __shared__ float part[4][4][64];  // [group][node][j], 4KB
  const int rounds = (n + 3) >> 2;
  for (int rb = blockIdx.x; rb < rounds; rb += gridDim.x) {
    const int i0 = rb * 4;
    const float* ab = agg + (size_t)i0 * 256 + tr * 64;
    float p0 = 0.f, p1 = 0.f, p2 = 0.f, p3 = 0.f;
#pragma unroll
    for (int q4 = 0; q4 < 16; ++q4) {
      const float4 b0 = *(const float4*)(ab + q4 * 4);
      const float4 b1 = *(const float4*)(ab + 256 + q4 * 4);
      const float4 b2 = *(const float4*)(ab + 512 + q4 * 4);
      const float4 b3 = *(const float4*)(ab + 768 + q4 * 4);
      const float w0 = wreg[q4 * 4], w1 = wreg[q4 * 4 + 1];
      const float w2 = wreg[q4 * 4 + 2], w3 = wreg[q4 * 4 + 3];
      p0 = fmaf(b0.x, w0, p0); p0 = fmaf(b0.y, w1, p0);
      p0 = fmaf(b0.z, w2, p0); p0 = fmaf(b0.w, w3, p0);
      p1 = fmaf(b1.x, w0, p1); p1 = fmaf(b1.y, w1, p1);
      p1 = fmaf(b1.z, w2, p1); p1 = fmaf(b1.w, w3, p1);
      p2 = fmaf(b2.x, w0, p2); p2 = fmaf(b2.y, w1, p2);
      p2 = fmaf(b2.z, w2, p2); p2 = fmaf(b2.w, w3, p2);
      p3 = fmaf(b3.x, w0, p3); p3 = fmaf(b3.y, w1, p3);
      p3 = fmaf(b3.z, w2, p3); p3 = fmaf(b3.w, w3, p3);
    }
    part[tr][0][j] = p0;
    part[tr][1][j] = p1;
    part[tr][2][j] = p2;
    part[tr][3][j] = p3;
    __syncthreads();
    const int i = i0 + tr;  // wave tr finishes node i0+tr
    if (i < n) {
      float out = fb[(size_t)i * 64 + j];
      out += part[0][tr][j] + part[1][tr][j] + part[2][tr][j] + part[3][tr][j];
      const size_t idx = (size_t)i * 64 + j;
      const float y = Yin[idx], x = X[idx];
      const float yn = fmaf(c_k, out, fmaf(c_x, x, c_decay * y));
      const float xn = fmaf(DT_F, yn, x);
      float sy = yn * yn, sx = xn * xn;
#pragma unroll
      for (int m = 32; m > 0; m >>= 1) {
        sy += __shfl_xor(sy, m);
        sx += __shfl_xor(sx, m);
      }
      Yout[idx] = yn * rsqrtf(sy * (1.f / 64.f) + EPS_F);
      X[idx] = xn * rsqrtf(sx * (1.f / 64.f) + EPS_F);
    }
    __syncthreads();
  }
}

// out[n,16] = X[n,64] @ dec_w[64,16] + dec_b
__global__ __launch_bounds__(256) void dec_kernel(
    const float* __restrict__ X, const float* __restrict__ w,
    const float* __restrict__ b, float* __restrict__ out, int n) {
  __shared__ float ws[64 * NCLS];
  for (int t = threadIdx.x; t < 64 * NCLS; t += blockDim.x) ws[t] = w[t];
  __syncthreads();
  const int t = threadIdx.x;
  const int jr = t & 15, ir = t >> 4;  // 16 rows / block
  for (int i0 = blockIdx.x * 16; i0 < n; i0 += gridDim.x * 16) {
    const int i = i0 + ir;
    if (i < n) {
      const float* xrow = X + (size_t)i * 64;
      float acc = b[jr];
#pragma unroll 8
      for (int k = 0; k < 64; ++k) acc = fmaf(xrow[k], ws[k * NCLS + jr], acc);
      out[(size_t)i * NCLS + jr] = acc;
    }
  }
}

static inline size_t alignup(size_t x) { return (x + 255) & ~(size_t)255; }

extern "C" void kernel_launch(void* const* d_in, const int* in_sizes, int n_in,
                              void* d_out, int out_size, void* d_ws, size_t ws_size,
                              hipStream_t stream) {
  const float* x     = (const float*)d_in[0];
  const float* enc_w = (const float*)d_in[1];
  const float* enc_b = (const float*)d_in[2];
  const float* dec_w = (const float*)d_in[3];
  const float* dec_b = (const float*)d_in[4];
  const float* lo_w  = (const float*)d_in[5];
  const float* lo_b  = (const float*)d_in[6];
  const float* dpl_w = (const float*)d_in[7];
  const float* dpl_b = (const float*)d_in[8];
  const float* dpr_w = (const float*)d_in[9];
  const float* dpr_b = (const float*)d_in[10];
  const float* lin_w = (const float*)d_in[11];
  const float* lin_b = (const float*)d_in[12];
  const float* att   = (const float*)d_in[13];
  const int*   ei    = (const int*)d_in[14];

  const int n = in_sizes[0] / NFEAT;
  const int E = in_sizes[14] / 2;
  const int* row = ei;
  const int* col = ei + E;

  // workspace carve-up
  char* p = (char*)d_ws;
  size_t off = 0;
  auto alloc = [&](size_t bytes) { void* r = p + off; off += alignup(bytes); return r; };
  float*  Y    = (float*)alloc((size_t)n * 64 * 4);
  float*  Y2   = (float*)alloc((size_t)n * 64 * 4);
  float*  X    = (float*)alloc((size_t)n * 64 * 4);
  float*  xl   = (float*)alloc((size_t)n * HC * 4);  // overlaid by agg after score
  float*  xr   = (float*)alloc((size_t)n * HC * 4);  // overlaid by fb after score
  float4* sw   = (float4*)alloc((size_t)E * 16);
  int*    srow = (int*)alloc((size_t)E * 4);
  int*    deg  = (int*)alloc((size_t)n * 4);
  int*    offs = (int*)alloc((size_t)(n + 1) * 4);
  int*    cur  = (int*)alloc((size_t)n * 4);
  float*  dis  = (float*)alloc((size_t)n * 4);
  float4* invq = (float4*)alloc((size_t)n * 16);
  float4* wq   = (float4*)alloc((size_t)n * 16);
  float*  Wext = (float*)alloc((size_t)HC * 64 * 4);
  float*  bb   = (float*)alloc((size_t)HC * 4);
  float*  agg  = xl;  // [n][256], xl dead after score
  float*  fb   = xr;  // [n][64],  xr dead after score

  // dynamics constants (softplus(1) in double, folded into update coefficients)
  const double sp = log1p(exp(1.0));  // omega = zeta = Ks
  const float c_decay = (float)(1.0 - 2.0 * sp * sp * 0.01);
  const float c_x     = (float)(-(sp * sp) * 0.01);
  const float c_k     = (float)(sp * 0.01);

  hipMemsetAsync(deg, 0, (size_t)n * 4, stream);

  enc_kernel<<<512, 256, 0, stream>>>(x, enc_w, enc_b, Y, X, n);
  rowgemm64_256<<<512, 256, 0, stream>>>(Y, dpl_w, dpl_b, xl, n);
  rowgemm64_256<<<512, 256, 0, stream>>>(Y, dpr_w, dpr_b, xr, n);
  wext_kernel<<<260, 64, 0, stream>>>(lin_w, lin_b, lo_w, Wext, bb);
  deg_kernel<<<(E + 255) / 256, 256, 0, stream>>>(col, deg, E);
  scan_kernel<<<1, 256, 0, stream>>>(deg, offs, cur, dis, invq, wq, n);
  scatter_kernel<<<(E + 255) / 256, 256, 0, stream>>>(row, col, cur, srow, E);
  score_kernel<<<(n + 3) / 4, 256, 0, stream>>>(offs, srow, (const float4*)xl,
                                                (const float4*)xr, att, dis, sw, invq,
                                                wq, n);
  fb_kernel<<<(n + 3) / 4, 256, 0, stream>>>(wq, bb, lo_b, fb, n);

  const float* Yin = Y;
  float* Yout = Y2;
  for (int l = 0; l < 4; ++l) {
    agg_kernel<<<(n + 3) / 4, 256, 0, stream>>>(offs, srow, sw, invq, Yin, agg, n);
    gemmupd_kernel<<<512, 256, 0, stream>>>(agg, Wext, fb, Yin, Yout, X, n,
                                            c_decay, c_x, c_k);
    const float* tmp = Yout; Yout = (float*)Yin; Yin = tmp;
  }
  dec_kernel<<<(n + 15) / 16, 256, 0, stream>>>(X, dec_w, dec_b, (float*)d_out, n);
}

// Round 4
// 226.968 us; speedup vs baseline: 1.8015x; 1.4367x over previous
//
#include <hip/hip_runtime.h>
#include <math.h>

#define NFEAT 128
#define HC    256   // HEADS*NHID
#define NCLS  16
#define DT_F  0.01f
#define EPS_F 1e-5f

__device__ __forceinline__ float bf2f(unsigned short u) {
  union { unsigned int u; float f; } v; v.u = ((unsigned int)u) << 16; return v.f;
}
__device__ __forceinline__ unsigned short f2bf(float f) {
  union { float f; unsigned int u; } v; v.f = f;
  unsigned int r = v.u + 0x7fffu + ((v.u >> 16) & 1u);
  return (unsigned short)(r >> 16);
}

// Y = relu(x @ enc_w + enc_b); X = Y; Ybf = bf16(Y).   x:[n,128] w:[128,64]
__global__ __launch_bounds__(256) void enc_kernel(
    const float* __restrict__ x, const float* __restrict__ w,
    const float* __restrict__ b, float* __restrict__ Y, float* __restrict__ X,
    unsigned short* __restrict__ Ybf, int n) {
  __shared__ float ws[NFEAT * 64];  // 32KB
  for (int t = threadIdx.x; t < NFEAT * 64; t += blockDim.x) ws[t] = w[t];
  __syncthreads();
  const int wave = threadIdx.x >> 6, lane = threadIdx.x & 63;
  for (int i = blockIdx.x * 4 + wave; i < n; i += gridDim.x * 4) {
    const float* xr = x + (size_t)i * NFEAT;
    float acc = b[lane];
#pragma unroll 8
    for (int k = 0; k < NFEAT; ++k) acc = fmaf(xr[k], ws[k * 64 + lane], acc);
    acc = fmaxf(acc, 0.f);
    const size_t idx = (size_t)i * 64 + lane;
    Y[idx] = acc;
    X[idx] = acc;
    Ybf[idx] = f2bf(acc);
  }
}

// Dual projection: blocks [0,half): xr = Y@dpr + br (fp32);
//                  blocks [half,2*half): xlb = bf16(Y@dpl + bl).
__global__ __launch_bounds__(256) void proj_kernel(
    const float* __restrict__ Y,
    const float* __restrict__ wl, const float* __restrict__ bl,
    const float* __restrict__ wr, const float* __restrict__ br,
    unsigned short* __restrict__ xlb, float* __restrict__ xr, int n) {
  const int half = gridDim.x >> 1;
  const bool doR = (int)blockIdx.x < half;
  const int bid = doR ? blockIdx.x : blockIdx.x - half;
  const float* __restrict__ W = doR ? wr : wl;
  const float* __restrict__ B = doR ? br : bl;
  float wreg[64];
  const int t = threadIdx.x;
#pragma unroll
  for (int k = 0; k < 64; ++k) wreg[k] = W[k * HC + t];
  const float bias = B[t];
  for (int i0 = bid * 4; i0 < n; i0 += half * 4) {
    const float* ap = Y + (size_t)i0 * 64;
    float a0 = bias, a1 = bias, a2 = bias, a3 = bias;
#pragma unroll
    for (int k = 0; k < 64; ++k) {
      const float w = wreg[k];
      a0 = fmaf(ap[k], w, a0);
      a1 = fmaf(ap[64 + k], w, a1);
      a2 = fmaf(ap[128 + k], w, a2);
      a3 = fmaf(ap[192 + k], w, a3);
    }
    if (doR) {
      if (i0 + 0 < n) xr[(size_t)(i0 + 0) * HC + t] = a0;
      if (i0 + 1 < n) xr[(size_t)(i0 + 1) * HC + t] = a1;
      if (i0 + 2 < n) xr[(size_t)(i0 + 2) * HC + t] = a2;
      if (i0 + 3 < n) xr[(size_t)(i0 + 3) * HC + t] = a3;
    } else {
      if (i0 + 0 < n) xlb[(size_t)(i0 + 0) * HC + t] = f2bf(a0);
      if (i0 + 1 < n) xlb[(size_t)(i0 + 1) * HC + t] = f2bf(a1);
      if (i0 + 2 < n) xlb[(size_t)(i0 + 2) * HC + t] = f2bf(a2);
      if (i0 + 3 < n) xlb[(size_t)(i0 + 3) * HC + t] = f2bf(a3);
    }
  }
}

// Wext[(k*4+h)*64 + j] = sum_c lin_w[k, h*64+c] * lo_w[h*64+c, j]   (b in 0..255)
// bb[h*64+j]           = sum_c lin_b[h*64+c]    * lo_w[h*64+c, j]   (b in 256..259)
__global__ __launch_bounds__(64) void wext_kernel(
    const float* __restrict__ lin_w, const float* __restrict__ lin_b,
    const float* __restrict__ lo_w, float* __restrict__ Wext, float* __restrict__ bb) {
  const int j = threadIdx.x;
  const int b = blockIdx.x;
  if (b < 256) {
    const int k = b >> 2, h = b & 3;
    float acc = 0.f;
#pragma unroll 8
    for (int c = 0; c < 64; ++c)
      acc = fmaf(lin_w[k * HC + h * 64 + c], lo_w[(size_t)(h * 64 + c) * 64 + j], acc);
    Wext[b * 64 + j] = acc;
  } else {
    const int h = b - 256;
    float acc = 0.f;
#pragma unroll 8
    for (int c = 0; c < 64; ++c)
      acc = fmaf(lin_b[h * 64 + c], lo_w[(size_t)(h * 64 + c) * 64 + j], acc);
    bb[h * 64 + j] = acc;
  }
}

__global__ __launch_bounds__(256) void deg_kernel(const int* __restrict__ col,
                                                  int* __restrict__ deg, int E) {
  int e = blockIdx.x * blockDim.x + threadIdx.x;
  if (e < E) atomicAdd(&deg[col[e]], 1);
}

// single-block exclusive scan over deg -> offsets/cursor, dis = deg^-0.5
__global__ __launch_bounds__(256) void scan_kernel(
    const int* __restrict__ deg, int* __restrict__ offsets, int* __restrict__ cursor,
    float* __restrict__ dis, int n) {
  __shared__ int part[256];
  const int t = threadIdx.x;
  const int chunk = (n + 255) / 256;
  const int start = t * chunk;
  const int end = min(start + chunk, n);
  int s = 0;
  for (int i = start; i < end; ++i) s += deg[i];
  part[t] = s;
  __syncthreads();
  for (int off = 1; off < 256; off <<= 1) {
    int v = (t >= off) ? part[t - off] : 0;
    __syncthreads();
    part[t] += v;
    __syncthreads();
  }
  int run = (t == 0) ? 0 : part[t - 1];
  for (int i = start; i < end; ++i) {
    offsets[i] = run;
    cursor[i] = run;
    int d = deg[i];
    dis[i] = (d > 0) ? rsqrtf((float)d) : 0.f;
    run += d;
  }
  if (t == 255) offsets[n] = run;
}

// counting-sort src indices into CSR order by destination
__global__ __launch_bounds__(256) void scatter_kernel(
    const int* __restrict__ row, const int* __restrict__ col,
    int* __restrict__ cursor, int* __restrict__ srow, int E) {
  int e = blockIdx.x * blockDim.x + threadIdx.x;
  if (e >= E) return;
  int pos = atomicAdd(&cursor[col[e]], 1);
  srow[pos] = row[e];
}

// Per dst node (one wave, CSR order): exp(logit)*dis[r] per edge -> sw;
// invq = dis[d]/ssum per head; fused fb[i][j] = lo_b[j] + sum_h wq_h*bb[h*64+j].
// Lane L covers flat channels L*4..L*4+3 (head h = L>>4). xl is bf16.
__global__ __launch_bounds__(256) void score_kernel(
    const int* __restrict__ offs, const int* __restrict__ srow,
    const ushort4* __restrict__ xlb4, const float4* __restrict__ xr4,
    const float* __restrict__ att, const float* __restrict__ dis,
    const float* __restrict__ bb, const float* __restrict__ lo_b,
    float4* __restrict__ sw, float4* __restrict__ invq, float* __restrict__ fb, int n) {
  const int wave = threadIdx.x >> 6, lane = threadIdx.x & 63;
  const int d = blockIdx.x * 4 + wave;
  if (d >= n) return;
  const int s = offs[d], e = offs[d + 1];
  if (s >= e) {  // isolated node: coupling_Y = lo_b
    if (lane == 0) invq[d] = make_float4(0.f, 0.f, 0.f, 0.f);
    fb[(size_t)d * 64 + lane] = lo_b[lane];
    return;
  }
  const float4 at4 = ((const float4*)att)[lane];
  const float4 r4 = xr4[(size_t)d * 64 + lane];
  const float dd = dis[d];
  float ssum = 0.f, wsum = 0.f;
  int p = s;
  for (; p + 1 < e; p += 2) {
    const int r0 = srow[p], r1 = srow[p + 1];
    const ushort4 u0 = xlb4[(size_t)r0 * 64 + lane];
    const ushort4 u1 = xlb4[(size_t)r1 * 64 + lane];
    const float di0 = dis[r0], di1 = dis[r1];
    float vx = bf2f(u0.x) + r4.x, vy = bf2f(u0.y) + r4.y;
    float vz = bf2f(u0.z) + r4.z, vw = bf2f(u0.w) + r4.w;
    vx = fmaxf(vx, 0.2f * vx); vy = fmaxf(vy, 0.2f * vy);
    vz = fmaxf(vz, 0.2f * vz); vw = fmaxf(vw, 0.2f * vw);
    float t0 = vx * at4.x;
    t0 = fmaf(vy, at4.y, t0); t0 = fmaf(vz, at4.z, t0); t0 = fmaf(vw, at4.w, t0);
    vx = bf2f(u1.x) + r4.x; vy = bf2f(u1.y) + r4.y;
    vz = bf2f(u1.z) + r4.z; vw = bf2f(u1.w) + r4.w;
    vx = fmaxf(vx, 0.2f * vx); vy = fmaxf(vy, 0.2f * vy);
    vz = fmaxf(vz, 0.2f * vz); vw = fmaxf(vw, 0.2f * vw);
    float t1 = vx * at4.x;
    t1 = fmaf(vy, at4.y, t1); t1 = fmaf(vz, at4.z, t1); t1 = fmaf(vw, at4.w, t1);
#pragma unroll
    for (int m = 1; m < 16; m <<= 1) {
      t0 += __shfl_xor(t0, m);
      t1 += __shfl_xor(t1, m);
    }
    const float a0 = __expf(t0), a1 = __expf(t1);
    ssum += a0 + a1;
    const float s0 = a0 * di0, s1 = a1 * di1;
    wsum += s0 + s1;
    if ((lane & 15) == 0) {
      ((float*)&sw[p])[lane >> 4] = s0;
      ((float*)&sw[p + 1])[lane >> 4] = s1;
    }
  }
  for (; p < e; ++p) {
    const int r0 = srow[p];
    const ushort4 u0 = xlb4[(size_t)r0 * 64 + lane];
    const float di0 = dis[r0];
    float vx = bf2f(u0.x) + r4.x, vy = bf2f(u0.y) + r4.y;
    float vz = bf2f(u0.z) + r4.z, vw = bf2f(u0.w) + r4.w;
    vx = fmaxf(vx, 0.2f * vx); vy = fmaxf(vy, 0.2f * vy);
    vz = fmaxf(vz, 0.2f * vz); vw = fmaxf(vw, 0.2f * vw);
    float t0 = vx * at4.x;
    t0 = fmaf(vy, at4.y, t0); t0 = fmaf(vz, at4.z, t0); t0 = fmaf(vw, at4.w, t0);
#pragma unroll
    for (int m = 1; m < 16; m <<= 1) t0 += __shfl_xor(t0, m);
    const float a0 = __expf(t0);
    ssum += a0;
    const float s0 = a0 * di0;
    wsum += s0;
    if ((lane & 15) == 0) ((float*)&sw[p])[lane >> 4] = s0;
  }
  const float inv = dd / (ssum > 0.f ? ssum : 1.f);
  const float wqv = wsum * inv;  // uniform within each 16-lane (head) group
  if ((lane & 15) == 0) ((float*)&invq[d])[lane >> 4] = inv;
  const float w0 = __shfl(wqv, 0), w1 = __shfl(wqv, 16);
  const float w2 = __shfl(wqv, 32), w3 = __shfl(wqv, 48);
  float v = lo_b[lane];
  v = fmaf(w0, bb[lane], v);
  v = fmaf(w1, bb[64 + lane], v);
  v = fmaf(w2, bb[128 + lane], v);
  v = fmaf(w3, bb[192 + lane], v);
  fb[(size_t)d * 64 + lane] = v;
}

// Fused per layer: wave-per-node CSR aggregation of bf16 Y (XCD-L2-resident)
// -> 8KB LDS handoff -> reg-partitioned [256x64] GEMM (4 waves cooperate on a
// 4-node quad) -> oscillator update + rmsnorm. 2 barriers per quad.
__global__ __launch_bounds__(256) void layer_fused(
    const int* __restrict__ offs, const int* __restrict__ srow,
    const float4* __restrict__ sw, const float4* __restrict__ invq,
    const unsigned short* __restrict__ ybf_in, const float* __restrict__ Wext,
    const float* __restrict__ fb, const float* __restrict__ Yin,
    float* __restrict__ Yout, unsigned short* __restrict__ ybf_out,
    float* __restrict__ X, int n, float c_decay, float c_x, float c_k) {
  const int t = threadIdx.x, tr = t >> 6, lane = t & 63;
  float wreg[64];
#pragma unroll
  for (int q = 0; q < 64; ++q) wreg[q] = Wext[(tr * 64 + q) * 64 + lane];
  __shared__ float aggl[4][HC];      // 4KB: [node][flat 256]
  __shared__ float partl[4][4][64];  // 4KB: [weight-group][node][j]
  const int rounds = (n + 3) >> 2;
  for (int rb = blockIdx.x; rb < rounds; rb += gridDim.x) {
    const int i = rb * 4 + tr;  // wave tr owns node i
    // phase 1: aggregate
    float4 o = make_float4(0.f, 0.f, 0.f, 0.f);
    if (i < n) {
      const int s = offs[i], e = offs[i + 1];
      float a0 = 0.f, a1 = 0.f, a2 = 0.f, a3 = 0.f;
      int p = s;
      for (; p + 3 < e; p += 4) {
        const int r0 = srow[p], r1 = srow[p + 1], r2 = srow[p + 2], r3 = srow[p + 3];
        const float4 v0 = sw[p], v1 = sw[p + 1], v2 = sw[p + 2], v3 = sw[p + 3];
        const float y0 = bf2f(ybf_in[(size_t)r0 * 64 + lane]);
        const float y1 = bf2f(ybf_in[(size_t)r1 * 64 + lane]);
        const float y2 = bf2f(ybf_in[(size_t)r2 * 64 + lane]);
        const float y3 = bf2f(ybf_in[(size_t)r3 * 64 + lane]);
        a0 = fmaf(v0.x, y0, a0); a1 = fmaf(v0.y, y0, a1);
        a2 = fmaf(v0.z, y0, a2); a3 = fmaf(v0.w, y0, a3);
        a0 = fmaf(v1.x, y1, a0); a1 = fmaf(v1.y, y1, a1);
        a2 = fmaf(v1.z, y1, a2); a3 = fmaf(v1.w, y1, a3);
        a0 = fmaf(v2.x, y2, a0); a1 = fmaf(v2.y, y2, a1);
        a2 = fmaf(v2.z, y2, a2); a3 = fmaf(v2.w, y2, a3);
        a0 = fmaf(v3.x, y3, a0); a1 = fmaf(v3.y, y3, a1);
        a2 = fmaf(v3.z, y3, a2); a3 = fmaf(v3.w, y3, a3);
      }
      for (; p < e; ++p) {
        const int r0 = srow[p];
        const float4 v0 = sw[p];
        const float y0 = bf2f(ybf_in[(size_t)r0 * 64 + lane]);
        a0 = fmaf(v0.x, y0, a0); a1 = fmaf(v0.y, y0, a1);
        a2 = fmaf(v0.z, y0, a2); a3 = fmaf(v0.w, y0, a3);
      }
      const float4 iv = invq[i];
      o.x = a0 * iv.x; o.y = a1 * iv.y; o.z = a2 * iv.z; o.w = a3 * iv.w;
    }
    ((float4*)aggl[tr])[lane] = o;  // aggl[tr][lane*4 + h] = agg flat element
    __syncthreads();
    // phase 2: GEMM — wave tr covers flat rows tr*64..tr*64+63 for all 4 nodes
    float p0 = 0.f, p1 = 0.f, p2 = 0.f, p3 = 0.f;
#pragma unroll
    for (int q4 = 0; q4 < 16; ++q4) {
      const float4 b0 = *(const float4*)(&aggl[0][tr * 64 + q4 * 4]);
      const float4 b1 = *(const float4*)(&aggl[1][tr * 64 + q4 * 4]);
      const float4 b2 = *(const float4*)(&aggl[2][tr * 64 + q4 * 4]);
      const float4 b3 = *(const float4*)(&aggl[3][tr * 64 + q4 * 4]);
      const float w0 = wreg[q4 * 4], w1 = wreg[q4 * 4 + 1];
      const float w2 = wreg[q4 * 4 + 2], w3 = wreg[q4 * 4 + 3];
      p0 = fmaf(b0.x, w0, p0); p0 = fmaf(b0.y, w1, p0);
      p0 = fmaf(b0.z, w2, p0); p0 = fmaf(b0.w, w3, p0);
      p1 = fmaf(b1.x, w0, p1); p1 = fmaf(b1.y, w1, p1);
      p1 = fmaf(b1.z, w2, p1); p1 = fmaf(b1.w, w3, p1);
      p2 = fmaf(b2.x, w0, p2); p2 = fmaf(b2.y, w1, p2);
      p2 = fmaf(b2.z, w2, p2); p2 = fmaf(b2.w, w3, p2);
      p3 = fmaf(b3.x, w0, p3); p3 = fmaf(b3.y, w1, p3);
      p3 = fmaf(b3.z, w2, p3); p3 = fmaf(b3.w, w3, p3);
    }
    partl[tr][0][lane] = p0;
    partl[tr][1][lane] = p1;
    partl[tr][2][lane] = p2;
    partl[tr][3][lane] = p3;
    __syncthreads();
    // phase 3: update node i
    if (i < n) {
      const size_t idx = (size_t)i * 64 + lane;
      float out = fb[idx];
      out += partl[0][tr][lane] + partl[1][tr][lane] +
             partl[2][tr][lane] + partl[3][tr][lane];
      const float y = Yin[idx], x = X[idx];
      const float yn = fmaf(c_k, out, fmaf(c_x, x, c_decay * y));
      const float xn = fmaf(DT_F, yn, x);
      float sy = yn * yn, sx = xn * xn;
#pragma unroll
      for (int m = 32; m > 0; m >>= 1) {
        sy += __shfl_xor(sy, m);
        sx += __shfl_xor(sx, m);
      }
      const float ynn = yn * rsqrtf(sy * (1.f / 64.f) + EPS_F);
      Yout[idx] = ynn;
      ybf_out[idx] = f2bf(ynn);
      X[idx] = xn * rsqrtf(sx * (1.f / 64.f) + EPS_F);
    }
    // no 3rd barrier needed: next round's aggl writes are ordered by the
    // collective arrival at the next __syncthreads() (phase-1 -> sync1)
  }
}

// out[n,16] = X[n,64] @ dec_w[64,16] + dec_b
__global__ __launch_bounds__(256) void dec_kernel(
    const float* __restrict__ X, const float* __restrict__ w,
    const float* __restrict__ b, float* __restrict__ out, int n) {
  __shared__ float ws[64 * NCLS];
  for (int t = threadIdx.x; t < 64 * NCLS; t += blockDim.x) ws[t] = w[t];
  __syncthreads();
  const int t = threadIdx.x;
  const int jr = t & 15, ir = t >> 4;  // 16 rows / block
  for (int i0 = blockIdx.x * 16; i0 < n; i0 += gridDim.x * 16) {
    const int i = i0 + ir;
    if (i < n) {
      const float* xrow = X + (size_t)i * 64;
      float acc = b[jr];
#pragma unroll 8
      for (int k = 0; k < 64; ++k) acc = fmaf(xrow[k], ws[k * NCLS + jr], acc);
      out[(size_t)i * NCLS + jr] = acc;
    }
  }
}

static inline size_t alignup(size_t x) { return (x + 255) & ~(size_t)255; }

extern "C" void kernel_launch(void* const* d_in, const int* in_sizes, int n_in,
                              void* d_out, int out_size, void* d_ws, size_t ws_size,
                              hipStream_t stream) {
  const float* x     = (const float*)d_in[0];
  const float* enc_w = (const float*)d_in[1];
  const float* enc_b = (const float*)d_in[2];
  const float* dec_w = (const float*)d_in[3];
  const float* dec_b = (const float*)d_in[4];
  const float* lo_w  = (const float*)d_in[5];
  const float* lo_b  = (const float*)d_in[6];
  const float* dpl_w = (const float*)d_in[7];
  const float* dpl_b = (const float*)d_in[8];
  const float* dpr_w = (const float*)d_in[9];
  const float* dpr_b = (const float*)d_in[10];
  const float* lin_w = (const float*)d_in[11];
  const float* lin_b = (const float*)d_in[12];
  const float* att   = (const float*)d_in[13];
  const int*   ei    = (const int*)d_in[14];

  const int n = in_sizes[0] / NFEAT;
  const int E = in_sizes[14] / 2;
  const int* row = ei;
  const int* col = ei + E;

  // workspace carve-up
  char* p = (char*)d_ws;
  size_t off = 0;
  auto alloc = [&](size_t bytes) { void* r = p + off; off += alignup(bytes); return r; };
  float*          Y    = (float*)alloc((size_t)n * 64 * 4);
  float*          Y2   = (float*)alloc((size_t)n * 64 * 4);
  float*          X    = (float*)alloc((size_t)n * 64 * 4);
  unsigned short* ybfA = (unsigned short*)alloc((size_t)n * 64 * 2);
  unsigned short* ybfB = (unsigned short*)alloc((size_t)n * 64 * 2);
  unsigned short* xlb  = (unsigned short*)alloc((size_t)n * HC * 2);
  float*          xr   = (float*)alloc((size_t)n * HC * 4);
  float4*         sw   = (float4*)alloc((size_t)E * 16);
  int*            srow = (int*)alloc((size_t)E * 4);
  int*            deg  = (int*)alloc((size_t)n * 4);
  int*            offs = (int*)alloc((size_t)(n + 1) * 4);
  int*            cur  = (int*)alloc((size_t)n * 4);
  float*          dis  = (float*)alloc((size_t)n * 4);
  float4*         invq = (float4*)alloc((size_t)n * 16);
  float*          fb   = (float*)alloc((size_t)n * 64 * 4);
  float*          Wext = (float*)alloc((size_t)HC * 64 * 4);
  float*          bb   = (float*)alloc((size_t)HC * 4);

  // dynamics constants (softplus(1) in double, folded into update coefficients)
  const double sp = log1p(exp(1.0));  // omega = zeta = Ks
  const float c_decay = (float)(1.0 - 2.0 * sp * sp * 0.01);
  const float c_x     = (float)(-(sp * sp) * 0.01);
  const float c_k     = (float)(sp * 0.01);

  hipMemsetAsync(deg, 0, (size_t)n * 4, stream);

  enc_kernel<<<512, 256, 0, stream>>>(x, enc_w, enc_b, Y, X, ybfA, n);
  proj_kernel<<<1024, 256, 0, stream>>>(Y, dpl_w, dpl_b, dpr_w, dpr_b, xlb, xr, n);
  wext_kernel<<<260, 64, 0, stream>>>(lin_w, lin_b, lo_w, Wext, bb);
  deg_kernel<<<(E + 255) / 256, 256, 0, stream>>>(col, deg, E);
  scan_kernel<<<1, 256, 0, stream>>>(deg, offs, cur, dis, n);
  scatter_kernel<<<(E + 255) / 256, 256, 0, stream>>>(row, col, cur, srow, E);
  score_kernel<<<(n + 3) / 4, 256, 0, stream>>>(offs, srow, (const ushort4*)xlb,
                                                (const float4*)xr, att, dis, bb, lo_b,
                                                sw, invq, fb, n);

  const float* Yin = Y;
  float* Yout = Y2;
  const unsigned short* ybf_in = ybfA;
  unsigned short* ybf_out = ybfB;
  for (int l = 0; l < 4; ++l) {
    layer_fused<<<1024, 256, 0, stream>>>(offs, srow, sw, invq, ybf_in, Wext, fb,
                                          Yin, Yout, ybf_out, X, n, c_decay, c_x, c_k);
    const float* ty = Yout; Yout = (float*)Yin; Yin = ty;
    const unsigned short* tb = ybf_out; ybf_out = (unsigned short*)ybf_in; ybf_in = tb;
  }
  dec_kernel<<<(n + 15) / 16, 256, 0, stream>>>(X, dec_w, dec_b, (float*)d_out, n);
}